// Round 3
// baseline (10210.058 us; speedup 1.0000x reference)
//
#include <hip/hip_runtime.h>
#include <stdint.h>

#define B_   32
#define T_   2048
#define D_   512
#define U_   256
#define TS_  64              // t rows per S1 workgroup
#define NSL  (T_/TS_)        // 32 slices per batch

typedef short          bf16x8 __attribute__((ext_vector_type(8)));
typedef unsigned short u16x4  __attribute__((ext_vector_type(4)));
typedef float          f32x4  __attribute__((ext_vector_type(4)));

__device__ __forceinline__ float bf2f(unsigned short u){
  union{unsigned int i; float f;} v; v.i = ((unsigned int)u)<<16; return v.f;
}
__device__ __forceinline__ unsigned short f2bf(float f){
  union{float f; unsigned int i;} v; v.f = f;
  unsigned int r = v.i + 0x7FFFu + ((v.i>>16)&1u);
  return (unsigned short)(r>>16);
}
__device__ __forceinline__ float ftanh(float x){
  float xx = fminf(fmaxf(x,-20.f),20.f);
  float t = __builtin_amdgcn_exp2f(xx * 2.885390082f);   // e^{2x}
  return (t-1.f)*__builtin_amdgcn_rcpf(t+1.f);
}
__device__ __forceinline__ float fexp(float x){
  return __builtin_amdgcn_exp2f(x*1.4426950408889634f);
}

// ---------------- X: bf16 copy of x (one-time, halves S1 stream) ----------
__global__ __launch_bounds__(256) void k_xbf(
    const float* __restrict__ x, unsigned short* __restrict__ xb)
{
  const int n = B_*T_*D_;
  int idx = (blockIdx.x*256 + threadIdx.x)*4;
  int stride = gridDim.x*256*4;
  for (; idx < n; idx += stride){
    float4 v = *(const float4*)(x+idx);
    u16x4 o; o.x=f2bf(v.x); o.y=f2bf(v.y); o.z=f2bf(v.z); o.w=f2bf(v.w);
    *(u16x4*)(xb+idx) = o;
  }
}

// ---------------- P: uxpb = x @ U_a + b_a  (fp32 in, bf16 MFMA) -----------
__global__ __launch_bounds__(256) void k_uxpb(
    const float* __restrict__ x,      // [M=65536][512]
    const float* __restrict__ Ua,     // [512][256]
    const float* __restrict__ ba,     // [256]
    unsigned short* __restrict__ uxpb)// [M][256] bf16
{
  __shared__ unsigned short As[64][40];   // padded rows
  __shared__ unsigned short Bs[64][40];   // transposed B: [n][k]
  int bx = blockIdx.x;
  int nt = bx & 3, mt = bx >> 2;
  int m0 = mt*64, n0 = nt*64;
  int tid = threadIdx.x;
  int lane = tid & 63, w = tid >> 6;
  int wm = w >> 1, wn = w & 1;

  f32x4 acc[2][2] = {};
  int ar = tid >> 2, ak = (tid & 3) * 8;   // A staging: row, k-off
  int bk = tid >> 3, bn = (tid & 7) * 8;   // B staging: k, n-off

  for (int k0 = 0; k0 < 512; k0 += 32) {
    const float* ap = x  + (long)(m0+ar)*512 + k0 + ak;
    const float* bp = Ua + (long)(k0+bk)*256 + n0 + bn;
    float4 a0 = *(const float4*)ap, a1 = *(const float4*)(ap+4);
    float4 b0 = *(const float4*)bp, b1 = *(const float4*)(bp+4);
    __syncthreads();
    unsigned short* as = &As[ar][ak];
    as[0]=f2bf(a0.x); as[1]=f2bf(a0.y); as[2]=f2bf(a0.z); as[3]=f2bf(a0.w);
    as[4]=f2bf(a1.x); as[5]=f2bf(a1.y); as[6]=f2bf(a1.z); as[7]=f2bf(a1.w);
    Bs[bn+0][bk]=f2bf(b0.x); Bs[bn+1][bk]=f2bf(b0.y);
    Bs[bn+2][bk]=f2bf(b0.z); Bs[bn+3][bk]=f2bf(b0.w);
    Bs[bn+4][bk]=f2bf(b1.x); Bs[bn+5][bk]=f2bf(b1.y);
    Bs[bn+6][bk]=f2bf(b1.z); Bs[bn+7][bk]=f2bf(b1.w);
    __syncthreads();
    #pragma unroll
    for (int mi = 0; mi < 2; ++mi) {
      bf16x8 a = *(const bf16x8*)&As[wm*32 + mi*16 + (lane&15)][(lane>>4)*8];
      #pragma unroll
      for (int ni = 0; ni < 2; ++ni) {
        bf16x8 b = *(const bf16x8*)&Bs[wn*32 + ni*16 + (lane&15)][(lane>>4)*8];
        acc[mi][ni] = __builtin_amdgcn_mfma_f32_16x16x32_bf16(a, b, acc[mi][ni], 0,0,0);
      }
    }
  }
  #pragma unroll
  for (int mi = 0; mi < 2; ++mi)
  #pragma unroll
  for (int ni = 0; ni < 2; ++ni) {
    int col = n0 + wn*32 + ni*16 + (lane&15);
    float bias = ba[col];
    #pragma unroll
    for (int r = 0; r < 4; ++r) {
      int row = m0 + wm*32 + mi*16 + (lane>>4)*4 + r;
      uxpb[(long)row*256 + col] = f2bf(acc[mi][ni][r] + bias);
    }
  }
}

// ---------------- I0: h0 = tanh(x[:,0] @ W_s), c = 0 ----------------------
__global__ __launch_bounds__(256) void k_init_h(
    const float* __restrict__ x,
    const float* __restrict__ Ws,   // [512][256]
    float* __restrict__ h0,         // [B][256]
    float* __restrict__ c_ws)
{
  int b = blockIdx.x, tid = threadIdx.x;
  __shared__ float xs[512];
  xs[tid]     = x[(long)b*T_*D_ + tid];
  xs[tid+256] = x[(long)b*T_*D_ + tid + 256];
  __syncthreads();
  float sum = 0.f;
  for (int k = 0; k < 512; ++k) sum = fmaf(xs[k], Ws[(long)k*256 + tid], sum);
  h0[b*256+tid] = ftanh(sum);
  c_ws[b*256+tid] = 0.f;
}

// ---------------- I1: hW partials from h0 ---------------------------------
__global__ __launch_bounds__(256) void k_init_hw(
    const float* __restrict__ Wa,   // [256][256]
    const float* __restrict__ h0,
    float* __restrict__ hW_part)    // [B][8][256]
{
  int wg = blockIdx.x; int b = wg>>3, j = wg&7;
  int tid = threadIdx.x;
  __shared__ float hn[32];
  if (tid < 32) hn[tid] = h0[b*256 + j*32 + tid];
  __syncthreads();
  float sum = 0.f;
  #pragma unroll 8
  for (int w2 = 0; w2 < 32; ++w2) sum = fmaf(hn[w2], Wa[(j*32+w2)*256 + tid], sum);
  hW_part[(b*8+j)*256 + tid] = sum;
}

// ---------------- S1: fused energies + online softmax + ctx partials ------
template<int XBF>
__global__ __launch_bounds__(256) void k_attn(
    const float* __restrict__ xf,              // [B][T][512] fp32
    const unsigned short* __restrict__ xb,     // [B][T][512] bf16 (if XBF)
    const unsigned short* __restrict__ uxpb,   // [B][T][256] bf16
    const float* __restrict__ Va,              // [256]
    const float* __restrict__ hW_part,         // [B][8][256]
    float* __restrict__ part_m,                // [B*NSL]
    float* __restrict__ part_s,
    float* __restrict__ part_ctx)              // [B*NSL][512]
{
  int wg = blockIdx.x;
  int b = wg >> 5;          // NSL = 32
  int sl = wg & 31;
  int tid = threadIdx.x, lane = tid & 63, w = tid >> 6;

  __shared__ float hws[256];
  __shared__ float wm[4], wsum[4];
  __shared__ float wctx[4][512];

  {
    float s = 0.f;
    #pragma unroll
    for (int j = 0; j < 8; ++j) s += hW_part[(b*8 + j)*256 + tid];
    hws[tid] = s;
  }
  __syncthreads();

  float4 vv = *(const float4*)(Va + lane*4);
  float va[4] = {vv.x, vv.y, vv.z, vv.w};
  float hw4[4];
  #pragma unroll
  for (int j = 0; j < 4; ++j) hw4[j] = hws[lane*4+j];

  float m = -1e30f, s = 0.f;
  float acc[8] = {0,0,0,0,0,0,0,0};

  int t0 = sl * TS_;
  for (int i = 0; i < TS_/4; ++i) {
    int t = t0 + w + i*4;
    long rowu = (long)b*T_ + t;
    const unsigned short* up = uxpb + rowu*256 + lane*4;
    uint2 uv = *(const uint2*)up;
    float e = 0.f;
    e = fmaf(ftanh(bf2f((unsigned short)(uv.x & 0xFFFF))      + hw4[0]), va[0], e);
    e = fmaf(ftanh(bf2f((unsigned short)(uv.x >> 16))         + hw4[1]), va[1], e);
    e = fmaf(ftanh(bf2f((unsigned short)(uv.y & 0xFFFF))      + hw4[2]), va[2], e);
    e = fmaf(ftanh(bf2f((unsigned short)(uv.y >> 16))         + hw4[3]), va[3], e);
    #pragma unroll
    for (int o = 1; o < 64; o <<= 1) e += __shfl_xor(e, o, 64);

    float p;
    if (e > m) {                      // wave-uniform branch
      float r = fexp(m - e);
      s = s * r + 1.f;
      #pragma unroll
      for (int j = 0; j < 8; ++j) acc[j] *= r;
      m = e; p = 1.f;
    } else {
      p = fexp(e - m);
      s += p;
    }

    float xv[8];
    if (XBF) {
      const unsigned short* xp = xb + rowu*512 + lane*8;
      uint4 q = *(const uint4*)xp;
      unsigned int qq[4] = {q.x, q.y, q.z, q.w};
      #pragma unroll
      for (int j = 0; j < 8; ++j)
        xv[j] = bf2f((unsigned short)((qq[j>>1] >> ((j&1)*16)) & 0xFFFF));
    } else {
      const float* xp = xf + rowu*512 + lane*8;
      float4 v0 = *(const float4*)xp, v1 = *(const float4*)(xp+4);
      xv[0]=v0.x; xv[1]=v0.y; xv[2]=v0.z; xv[3]=v0.w;
      xv[4]=v1.x; xv[5]=v1.y; xv[6]=v1.z; xv[7]=v1.w;
    }
    #pragma unroll
    for (int j = 0; j < 8; ++j) acc[j] = fmaf(p, xv[j], acc[j]);
  }

  if (lane == 0) { wm[w] = m; wsum[w] = s; }
  #pragma unroll
  for (int j = 0; j < 8; ++j) wctx[w][lane*8+j] = acc[j];
  __syncthreads();

  float M = fmaxf(fmaxf(wm[0],wm[1]), fmaxf(wm[2],wm[3]));
  float f0 = fexp(wm[0]-M), f1 = fexp(wm[1]-M), f2 = fexp(wm[2]-M), f3 = fexp(wm[3]-M);
  #pragma unroll
  for (int d = tid; d < 512; d += 256) {
    float c = wctx[0][d]*f0 + wctx[1][d]*f1 + wctx[2][d]*f2 + wctx[3][d]*f3;
    part_ctx[(long)wg*512 + d] = c;
  }
  if (tid == 0) {
    part_m[wg] = M;
    part_s[wg] = wsum[0]*f0 + wsum[1]*f1 + wsum[2]*f2 + wsum[3]*f3;
  }
}

// ---------------- S2: combine + gates + h/c update + next hW partials -----
__global__ __launch_bounds__(256) void k_step(
    const float* __restrict__ Wk,   // kernel [512][1024]
    const float* __restrict__ Wr,   // recurrent [256][1024]
    const float* __restrict__ bias, // [1024]
    const float* __restrict__ Wa,   // [256][256]
    const float* __restrict__ part_m,
    const float* __restrict__ part_s,
    const float* __restrict__ part_ctx,
    const float* __restrict__ h_in,          // [B][256]
    float* __restrict__ h_out,               // [B][256]
    float* __restrict__ c_ws,                // [B][256]
    float* __restrict__ hW_part,             // [B][8][256]
    float* __restrict__ out,                 // [B][TDEC][256] fp32
    int step, int TDEC)
{
  int wg = blockIdx.x;
  int b = wg >> 3, j = wg & 7;
  int tid = threadIdx.x;

  __shared__ float ctx[512];
  __shared__ float hsh[256];
  __shared__ float zp[2][128];
  __shared__ float hn[32];
  __shared__ float wfac[32];

  // softmax combine factors
  float M = -1e30f;
  #pragma unroll
  for (int i = 0; i < NSL; ++i) M = fmaxf(M, part_m[b*NSL+i]);
  float S = 0.f;
  #pragma unroll
  for (int i = 0; i < NSL; ++i) S += part_s[b*NSL+i]*fexp(part_m[b*NSL+i]-M);
  if (tid < 32) wfac[tid] = fexp(part_m[b*NSL+tid]-M) / S;
  hsh[tid] = h_in[b*256 + tid];
  __syncthreads();

  #pragma unroll
  for (int d = tid; d < 512; d += 256) {
    float c = 0.f;
    #pragma unroll 8
    for (int i = 0; i < NSL; ++i)
      c = fmaf(part_ctx[(long)(b*NSL+i)*512 + d], wfac[i], c);
    ctx[d] = c;
  }
  __syncthreads();

  // z GEMV: 128 cols (4 gates x 32 u) split across 2 K-halves
  int c_  = tid & 127, half = tid >> 7;
  int g   = c_ >> 5, uu = j*32 + (c_ & 31);
  int col = g*256 + uu;
  float z = 0.f;
  if (half == 0) {
    for (int k = 0; k < 384; ++k) z = fmaf(ctx[k], Wk[(long)k*1024 + col], z);
  } else {
    for (int k = 384; k < 512; ++k) z = fmaf(ctx[k], Wk[(long)k*1024 + col], z);
    for (int k = 0; k < 256; ++k)   z = fmaf(hsh[k], Wr[(long)k*1024 + col], z);
  }
  zp[half][c_] = z;
  __syncthreads();
  if (tid < 128) zp[0][tid] = zp[0][tid] + zp[1][tid] + bias[col];
  __syncthreads();

  if (tid < 32) {
    float zi = zp[0][tid], zf = zp[0][32+tid], zc = zp[0][64+tid], zo = zp[0][96+tid];
    float ig = fminf(fmaxf(0.2f*zi+0.5f, 0.f), 1.f);
    float fg = fminf(fmaxf(0.2f*zf+0.5f, 0.f), 1.f);
    float og = fminf(fmaxf(0.2f*zo+0.5f, 0.f), 1.f);
    int u = j*32 + tid;
    float c_old = c_ws[b*256+u];
    float c_new = fg*c_old + ig*ftanh(zc);
    float h_new = og*ftanh(c_new);
    c_ws[b*256+u]  = c_new;
    h_out[b*256+u] = h_new;
    out[((long)b*TDEC + step)*256 + u] = h_new;
    hn[tid] = h_new;
  }
  __syncthreads();

  // next-step hW partial: rank-32 contribution of this u-slice
  {
    float sum = 0.f;
    #pragma unroll 8
    for (int w2 = 0; w2 < 32; ++w2)
      sum = fmaf(hn[w2], Wa[(j*32+w2)*256 + tid], sum);
    hW_part[(b*8+j)*256 + tid] = sum;
  }
}

// ---------------------------------------------------------------------------
extern "C" void kernel_launch(void* const* d_in, const int* in_sizes, int n_in,
                              void* d_out, int out_size, void* d_ws, size_t ws_size,
                              hipStream_t stream)
{
  const float* x  = (const float*)d_in[0];
  const float* Ws = (const float*)d_in[1];
  const float* Ua = (const float*)d_in[2];
  const float* ba = (const float*)d_in[3];
  const float* Wa = (const float*)d_in[4];
  const float* Va = (const float*)d_in[5];
  const float* Wk = (const float*)d_in[6];
  const float* Wr = (const float*)d_in[7];
  const float* bs = (const float*)d_in[8];
  int TDEC = out_size / (B_ * U_);   // decode_steps

  size_t off = 0;
  char* base = (char*)d_ws;
  unsigned short* uxpb = (unsigned short*)(base+off); off += (size_t)B_*T_*U_*2;
  float* part_ctx = (float*)(base+off);               off += (size_t)B_*NSL*512*4;
  float* part_m   = (float*)(base+off);               off += (size_t)B_*NSL*4;
  float* part_s   = (float*)(base+off);               off += (size_t)B_*NSL*4;
  float* hW_part  = (float*)(base+off);               off += (size_t)B_*8*U_*4;
  float* h_buf    = (float*)(base+off);               off += (size_t)2*B_*U_*4;
  float* c_ws     = (float*)(base+off);               off += (size_t)B_*U_*4;
  unsigned short* x_bf = (unsigned short*)(base+off); off += (size_t)B_*T_*D_*2;
  bool use_xbf = (off <= ws_size);

  k_uxpb  <<<(B_*T_/64)*(U_/64), 256, 0, stream>>>(x, Ua, ba, uxpb);
  if (use_xbf) k_xbf<<<2048, 256, 0, stream>>>(x, x_bf);
  k_init_h<<<B_,  256, 0, stream>>>(x, Ws, h_buf, c_ws);
  k_init_hw<<<B_*8, 256, 0, stream>>>(Wa, h_buf, hW_part);

  for (int s = 0; s < TDEC; ++s) {
    float* h_in  = h_buf + (s & 1)     * B_ * U_;
    float* h_out = h_buf + ((s+1) & 1) * B_ * U_;
    if (use_xbf)
      k_attn<1><<<B_*NSL, 256, 0, stream>>>(x, x_bf, uxpb, Va, hW_part,
                                            part_m, part_s, part_ctx);
    else
      k_attn<0><<<B_*NSL, 256, 0, stream>>>(x, x_bf, uxpb, Va, hW_part,
                                            part_m, part_s, part_ctx);
    k_step<<<B_*8,  256, 0, stream>>>(Wk, Wr, bs, Wa, part_m, part_s, part_ctx,
                                      h_in, h_out, c_ws, hW_part,
                                      (float*)d_out, s, TDEC);
  }
}